// Round 3
// baseline (754.874 us; speedup 1.0000x reference)
//
#include <hip/hip_runtime.h>
#include <math.h>

// ---------------------------------------------------------------------------
// 2-layer GCN on MI355X — linked-list aggregation (no CSR scatter).
// edge_index arrives as int32 [2][E] flat: first E = sources, next E = targets.
// Pipeline per launch (graph-capture safe, no statics):
//   1. memset cnt=0, head=0xFF(-1)
//   2. build: per edge e with target c: cnt[c]++, next[e]=atomicExch(head[c],e)
//      (next write is coalesced; only head is a 400KB L2-resident scatter)
//   3. dinv[i] = rsqrt(cnt[i]+1)
//   4. h1s = dinv .* (x @ W1)                       [f32 reg-tiled GEMM]
//   5. a1  = relu(dinv[c]*(sum_list h1s[src] + h1s[c]) + b1)  [list-walk gather]
//   6. h2s = dinv .* (a1 @ W2)
//   7. out = dinv[c]*(sum_list h2s[src] + h2s[c]) + b2
// ---------------------------------------------------------------------------

__global__ void build_kernel(const int* __restrict__ ei, int E,
                             int* __restrict__ cnt, int* __restrict__ head,
                             int* __restrict__ next, int N) {
  int e = blockIdx.x * blockDim.x + threadIdx.x;
  if (e < E) {
    int c = ei[(size_t)E + e];  // target
    if ((unsigned)c < (unsigned)N) {
      atomicAdd(&cnt[c], 1);
      int old = atomicExch(&head[c], e);
      next[e] = old;            // coalesced store
    } else {
      next[e] = -1;
    }
  }
}

__global__ void dinv_kernel(const int* __restrict__ cnt, float* __restrict__ dinv,
                            int N) {
  int i = blockIdx.x * blockDim.x + threadIdx.x;
  if (i < N) dinv[i] = 1.0f / sqrtf((float)cnt[i] + 1.0f);  // deg incl self-loop
}

// out[n][c] = dinv[n] * sum_k A[n][k] * W[k][c]
// Register tile 4 rows x 8 cols per thread; K chunked by 64 through LDS.
template <int K, int NC, int RB>
__global__ __launch_bounds__(256) void gemm_scaled(const float* __restrict__ A,
                                                   const float* __restrict__ W,
                                                   const float* __restrict__ dinv,
                                                   float* __restrict__ out, int N) {
  constexpr int KC = 64;
  constexpr int TX = NC / 8;   // col groups
  constexpr int TY = RB / 4;   // row groups
  static_assert(TX * TY == 256, "bad tile");
  static_assert(K % KC == 0, "bad K");
  __shared__ float wl[KC * NC];
  __shared__ float xl[RB][KC + 1];   // +1 pad: conflict-free column reads

  int t = threadIdx.x;
  int tx = t % TX, ty = t / TX;
  int c0 = tx * 8;
  int r0 = blockIdx.x * RB;

  float acc[4][8];
#pragma unroll
  for (int r = 0; r < 4; ++r)
#pragma unroll
    for (int c = 0; c < 8; ++c) acc[r][c] = 0.f;

  for (int k0 = 0; k0 < K; k0 += KC) {
    __syncthreads();
    {  // stage W chunk [KC][NC]
      const float4* Wg = reinterpret_cast<const float4*>(W + (size_t)k0 * NC);
      float4* wl4 = reinterpret_cast<float4*>(wl);
      constexpr int n4 = KC * NC / 4;
#pragma unroll
      for (int i0 = 0; i0 < n4 / 256; ++i0) wl4[t + i0 * 256] = Wg[t + i0 * 256];
    }
    {  // stage x chunk [RB][KC]
      constexpr int n4 = RB * KC / 4;
#pragma unroll
      for (int i0 = 0; i0 < n4 / 256; ++i0) {
        int i = t + i0 * 256;
        int rr = i / (KC / 4);
        int k4 = i % (KC / 4);
        int grow = min(r0 + rr, N - 1);
        float4 v = *reinterpret_cast<const float4*>(&A[(size_t)grow * K + k0 + k4 * 4]);
        xl[rr][k4 * 4 + 0] = v.x;
        xl[rr][k4 * 4 + 1] = v.y;
        xl[rr][k4 * 4 + 2] = v.z;
        xl[rr][k4 * 4 + 3] = v.w;
      }
    }
    __syncthreads();
#pragma unroll 8
    for (int kk = 0; kk < KC; ++kk) {
      const float4* wrow = reinterpret_cast<const float4*>(&wl[kk * NC + c0]);
      float4 w0 = wrow[0], w1 = wrow[1];
      float wv[8] = {w0.x, w0.y, w0.z, w0.w, w1.x, w1.y, w1.z, w1.w};
      float xv[4];
#pragma unroll
      for (int r = 0; r < 4; ++r) xv[r] = xl[ty * 4 + r][kk];
#pragma unroll
      for (int r = 0; r < 4; ++r)
#pragma unroll
        for (int c = 0; c < 8; ++c) acc[r][c] = fmaf(xv[r], wv[c], acc[r][c]);
    }
  }

#pragma unroll
  for (int r = 0; r < 4; ++r) {
    int grow = r0 + ty * 4 + r;
    if (grow < N) {
      float s = dinv[grow];
      float4 o0 = make_float4(acc[r][0] * s, acc[r][1] * s, acc[r][2] * s, acc[r][3] * s);
      float4 o1 = make_float4(acc[r][4] * s, acc[r][5] * s, acc[r][6] * s, acc[r][7] * s);
      float4* op = reinterpret_cast<float4*>(&out[(size_t)grow * NC + c0]);
      op[0] = o0;
      op[1] = o1;
    }
  }
}

// One wave per node; lane owns F/64 dims. Pull-gather via linked-list walk.
// Chain loads (next[cur], ei[cur]) are wave-uniform -> single broadcast line
// each; latency ~L3, hidden by ~8K nodes in flight. Gather stays BW-bound.
template <int F, bool RELU>
__global__ __launch_bounds__(256) void aggregate_ll(
    const float* __restrict__ hs, const int* __restrict__ head,
    const int* __restrict__ next, const int* __restrict__ ei,
    const float* __restrict__ dinv, const float* __restrict__ bias,
    float* __restrict__ out, int N) {
  int node = blockIdx.x * 4 + (threadIdx.x >> 6);
  if (node >= N) return;  // wave-uniform
  int lane = threadIdx.x & 63;
  float scale = dinv[node];
  int cur = __builtin_amdgcn_readfirstlane(head[node]);
  if constexpr (F == 128) {
    float2 acc = reinterpret_cast<const float2*>(hs + (size_t)node * F)[lane];  // self
    while (cur >= 0) {
      int nxt = __builtin_amdgcn_readfirstlane(next[cur]);
      int r = __builtin_amdgcn_readfirstlane(ei[cur]);  // source of edge cur
      if ((unsigned)r < (unsigned)N) {
        float2 v = reinterpret_cast<const float2*>(hs + (size_t)r * F)[lane];
        acc.x += v.x;
        acc.y += v.y;
      }
      cur = nxt;
    }
    float2 b = reinterpret_cast<const float2*>(bias)[lane];
    float ox = fmaf(scale, acc.x, b.x);
    float oy = fmaf(scale, acc.y, b.y);
    if (RELU) {
      ox = fmaxf(ox, 0.f);
      oy = fmaxf(oy, 0.f);
    }
    reinterpret_cast<float2*>(out + (size_t)node * F)[lane] = make_float2(ox, oy);
  } else {
    float acc = hs[(size_t)node * F + lane];  // self
    while (cur >= 0) {
      int nxt = __builtin_amdgcn_readfirstlane(next[cur]);
      int r = __builtin_amdgcn_readfirstlane(ei[cur]);
      if ((unsigned)r < (unsigned)N) acc += hs[(size_t)r * F + lane];
      cur = nxt;
    }
    float o = fmaf(scale, acc, bias[lane]);
    if (RELU) o = fmaxf(o, 0.f);
    out[(size_t)node * F + lane] = o;
  }
}

extern "C" void kernel_launch(void* const* d_in, const int* in_sizes, int n_in,
                              void* d_out, int out_size, void* d_ws, size_t ws_size,
                              hipStream_t stream) {
  const float* x = (const float*)d_in[0];
  const int* ei = (const int*)d_in[1];   // int32 on device (harness converts)
  const float* W1 = (const float*)d_in[2];
  const float* b1 = (const float*)d_in[3];
  const float* W2 = (const float*)d_in[4];
  const float* b2 = (const float*)d_in[5];
  float* out = (float*)d_out;

  const int IN = 256, HID = 128;
  int N = in_sizes[0] / IN;   // 100000
  int E = in_sizes[1] / 2;    // 1600000

  char* ws = (char*)d_ws;
  size_t off = 0;
  auto alloc = [&](size_t bytes) -> void* {
    void* p = ws + off;
    off += (bytes + 255) & ~(size_t)255;
    return p;
  };
  int* cnt = (int*)alloc((size_t)N * 4);
  int* head = (int*)alloc((size_t)N * 4);
  int* next = (int*)alloc((size_t)E * 4);
  float* dinv = (float*)alloc((size_t)N * 4);
  float* h1s = (float*)alloc((size_t)N * HID * 4);
  float* a1 = (float*)alloc((size_t)N * HID * 4);
  float* h2s = h1s;  // h1s dead after aggregate1 -> reuse for layer-2 GEMM out

  hipMemsetAsync(cnt, 0, (size_t)N * 4, stream);
  hipMemsetAsync(head, 0xFF, (size_t)N * 4, stream);  // -1 sentinels
  int eb = (E + 255) / 256;
  build_kernel<<<eb, 256, 0, stream>>>(ei, E, cnt, head, next, N);
  dinv_kernel<<<(N + 255) / 256, 256, 0, stream>>>(cnt, dinv, N);

  gemm_scaled<256, 128, 64><<<(N + 63) / 64, 256, 0, stream>>>(x, W1, dinv, h1s, N);
  aggregate_ll<128, true><<<(N + 3) / 4, 256, 0, stream>>>(h1s, head, next, ei, dinv, b1, a1, N);
  gemm_scaled<128, 64, 128><<<(N + 127) / 128, 256, 0, stream>>>(a1, W2, dinv, h2s, N);
  aggregate_ll<64, false><<<(N + 3) / 4, 256, 0, stream>>>(h2s, head, next, ei, dinv, b2, out, N);
}

// Round 4
// 679.722 us; speedup vs baseline: 1.1106x; 1.1106x over previous
//
#include <hip/hip_runtime.h>
#include <math.h>

// ---------------------------------------------------------------------------
// 2-layer GCN on MI355X — CSR pull aggregation, XCD-ownership CSR fill.
// edge_index arrives as int32 [2][E] flat: first E = sources, next E = targets.
// Pipeline per launch (graph-capture safe, no statics):
//   1. memset cnt; histogram of edge targets (int atomics)
//   2. exclusive scan -> CSR offsets (3-kernel scan)
//   3. finalize: offsets += block bases, cursor = offsets, dinv = 1/sqrt(deg+1)
//   4. fill CSR row-index array, XCD-partitioned by target range so each csr
//      cache line is written by ONE XCD's L2 (write-combine; ~6.4MB not 105MB)
//   5. h1s = dinv .* (x @ W1)                      [f32 reg-tiled GEMM]
//   6. a1  = relu(dinv[col]*(sum_nbr h1s + h1s[col]) + b1)   [pull gather]
//   7. h2s = dinv .* (a1 @ W2)
//   8. out = dinv[col]*(sum_nbr h2s + h2s[col]) + b2
// ---------------------------------------------------------------------------

__global__ void hist_kernel(const int* __restrict__ ei, int E,
                            int* __restrict__ cnt, int N) {
  int e = blockIdx.x * blockDim.x + threadIdx.x;
  if (e < E) {
    int c = ei[(size_t)E + e];  // col = target
    if ((unsigned)c < (unsigned)N) atomicAdd(&cnt[c], 1);
  }
}

__global__ __launch_bounds__(256) void scan_partial(const int* __restrict__ cnt,
                                                    int* __restrict__ offs,
                                                    int* __restrict__ bsums,
                                                    int N) {
  __shared__ int s[256];
  int t = threadIdx.x;
  int base = blockIdx.x * 1024 + t * 4;
  int v0 = (base + 0 < N) ? cnt[base + 0] : 0;
  int v1 = (base + 1 < N) ? cnt[base + 1] : 0;
  int v2 = (base + 2 < N) ? cnt[base + 2] : 0;
  int v3 = (base + 3 < N) ? cnt[base + 3] : 0;
  int sum = v0 + v1 + v2 + v3;
  s[t] = sum;
  __syncthreads();
#pragma unroll
  for (int d = 1; d < 256; d <<= 1) {
    int x = (t >= d) ? s[t - d] : 0;
    __syncthreads();
    s[t] += x;
    __syncthreads();
  }
  int excl = s[t] - sum;  // exclusive over thread sums within block
  if (base + 0 < N) offs[base + 0] = excl;
  if (base + 1 < N) offs[base + 1] = excl + v0;
  if (base + 2 < N) offs[base + 2] = excl + v0 + v1;
  if (base + 3 < N) offs[base + 3] = excl + v0 + v1 + v2;
  if (t == 255) bsums[blockIdx.x] = s[255];
}

__global__ __launch_bounds__(256) void scan_bsums(int* __restrict__ bsums, int nb) {
  // nb <= 256 (N=100K -> nb=98)
  __shared__ int s[256];
  int t = threadIdx.x;
  int v = (t < nb) ? bsums[t] : 0;
  s[t] = v;
  __syncthreads();
#pragma unroll
  for (int d = 1; d < 256; d <<= 1) {
    int x = (t >= d) ? s[t - d] : 0;
    __syncthreads();
    s[t] += x;
    __syncthreads();
  }
  if (t < nb) bsums[t] = s[t] - v;  // exclusive
}

__global__ void finalize_kernel(const int* __restrict__ cnt, int* __restrict__ offs,
                                int* __restrict__ cursor, float* __restrict__ dinv,
                                const int* __restrict__ bsums, int N, int E) {
  int i = blockIdx.x * blockDim.x + threadIdx.x;
  if (i < N) {
    int o = offs[i] + bsums[i >> 10];
    offs[i] = o;
    cursor[i] = o;
    dinv[i] = 1.0f / sqrtf((float)cnt[i] + 1.0f);  // deg includes self-loop
    if (i == 0) offs[N] = E;
  }
}

// XCD-ownership fill: block -> XCD via blockIdx&7 (round-robin dispatch).
// Each XCD scans ALL edge targets (8x sequential re-read, cheap) but only
// handles targets in its owned node range -> each csr line written by one
// XCD, write-combined in its L2, written back once.
__global__ __launch_bounds__(256) void fill_swz(const int* __restrict__ ei, int E,
                                                int* __restrict__ cursor,
                                                int* __restrict__ csr,
                                                int N, int npx, int nbg) {
  int xcd = blockIdx.x & 7;
  int grp = blockIdx.x >> 3;
  int lo = xcd * npx;
  int hi = min(N, lo + npx);
  for (int e = grp * 256 + threadIdx.x; e < E; e += nbg * 256) {
    int c = ei[(size_t)E + e];  // target
    if (c >= lo && c < hi) {
      int r = ei[e];            // source
      if ((unsigned)r < (unsigned)N) {
        int p = atomicAdd(&cursor[c], 1);
        if ((unsigned)p < (unsigned)E) csr[p] = r;
      }
    }
  }
}

// out[n][c] = dinv[n] * sum_k A[n][k] * W[k][c]
// Register tile 4 rows x 8 cols per thread; K chunked by 64 through LDS.
template <int K, int NC, int RB>
__global__ __launch_bounds__(256) void gemm_scaled(const float* __restrict__ A,
                                                   const float* __restrict__ W,
                                                   const float* __restrict__ dinv,
                                                   float* __restrict__ out, int N) {
  constexpr int KC = 64;
  constexpr int TX = NC / 8;   // col groups
  constexpr int TY = RB / 4;   // row groups
  static_assert(TX * TY == 256, "bad tile");
  static_assert(K % KC == 0, "bad K");
  __shared__ float wl[KC * NC];
  __shared__ float xl[RB][KC + 1];   // +1 pad: conflict-free column reads

  int t = threadIdx.x;
  int tx = t % TX, ty = t / TX;
  int c0 = tx * 8;
  int r0 = blockIdx.x * RB;

  float acc[4][8];
#pragma unroll
  for (int r = 0; r < 4; ++r)
#pragma unroll
    for (int c = 0; c < 8; ++c) acc[r][c] = 0.f;

  for (int k0 = 0; k0 < K; k0 += KC) {
    __syncthreads();
    {  // stage W chunk [KC][NC]
      const float4* Wg = reinterpret_cast<const float4*>(W + (size_t)k0 * NC);
      float4* wl4 = reinterpret_cast<float4*>(wl);
      constexpr int n4 = KC * NC / 4;
#pragma unroll
      for (int i0 = 0; i0 < n4 / 256; ++i0) wl4[t + i0 * 256] = Wg[t + i0 * 256];
    }
    {  // stage x chunk [RB][KC]
      constexpr int n4 = RB * KC / 4;
#pragma unroll
      for (int i0 = 0; i0 < n4 / 256; ++i0) {
        int i = t + i0 * 256;
        int rr = i / (KC / 4);
        int k4 = i % (KC / 4);
        int grow = min(r0 + rr, N - 1);
        float4 v = *reinterpret_cast<const float4*>(&A[(size_t)grow * K + k0 + k4 * 4]);
        xl[rr][k4 * 4 + 0] = v.x;
        xl[rr][k4 * 4 + 1] = v.y;
        xl[rr][k4 * 4 + 2] = v.z;
        xl[rr][k4 * 4 + 3] = v.w;
      }
    }
    __syncthreads();
#pragma unroll 8
    for (int kk = 0; kk < KC; ++kk) {
      const float4* wrow = reinterpret_cast<const float4*>(&wl[kk * NC + c0]);
      float4 w0 = wrow[0], w1 = wrow[1];
      float wv[8] = {w0.x, w0.y, w0.z, w0.w, w1.x, w1.y, w1.z, w1.w};
      float xv[4];
#pragma unroll
      for (int r = 0; r < 4; ++r) xv[r] = xl[ty * 4 + r][kk];
#pragma unroll
      for (int r = 0; r < 4; ++r)
#pragma unroll
        for (int c = 0; c < 8; ++c) acc[r][c] = fmaf(xv[r], wv[c], acc[r][c]);
    }
  }

#pragma unroll
  for (int r = 0; r < 4; ++r) {
    int grow = r0 + ty * 4 + r;
    if (grow < N) {
      float s = dinv[grow];
      float4 o0 = make_float4(acc[r][0] * s, acc[r][1] * s, acc[r][2] * s, acc[r][3] * s);
      float4 o1 = make_float4(acc[r][4] * s, acc[r][5] * s, acc[r][6] * s, acc[r][7] * s);
      float4* op = reinterpret_cast<float4*>(&out[(size_t)grow * NC + c0]);
      op[0] = o0;
      op[1] = o1;
    }
  }
}

// One wave per node; lane owns F/64 dims. Pull-gather over CSR.
template <int F, bool RELU>
__global__ __launch_bounds__(256) void aggregate_kernel(
    const float* __restrict__ hs, const int* __restrict__ offs,
    const int* __restrict__ csr, const float* __restrict__ dinv,
    const float* __restrict__ bias, float* __restrict__ out, int N) {
  int node = blockIdx.x * 4 + (threadIdx.x >> 6);
  if (node >= N) return;  // wave-uniform
  int lane = threadIdx.x & 63;
  int beg = __builtin_amdgcn_readfirstlane(offs[node]);
  int end = __builtin_amdgcn_readfirstlane(offs[node + 1]);
  float scale = dinv[node];
  if constexpr (F == 128) {
    float2 acc = reinterpret_cast<const float2*>(hs + (size_t)node * F)[lane];  // self
    for (int j = beg; j < end; ++j) {
      int r = csr[j];
      float2 v = reinterpret_cast<const float2*>(hs + (size_t)r * F)[lane];
      acc.x += v.x;
      acc.y += v.y;
    }
    float2 b = reinterpret_cast<const float2*>(bias)[lane];
    float ox = fmaf(scale, acc.x, b.x);
    float oy = fmaf(scale, acc.y, b.y);
    if (RELU) {
      ox = fmaxf(ox, 0.f);
      oy = fmaxf(oy, 0.f);
    }
    reinterpret_cast<float2*>(out + (size_t)node * F)[lane] = make_float2(ox, oy);
  } else {
    float acc = hs[(size_t)node * F + lane];  // self
    for (int j = beg; j < end; ++j) {
      int r = csr[j];
      acc += hs[(size_t)r * F + lane];
    }
    float o = fmaf(scale, acc, bias[lane]);
    if (RELU) o = fmaxf(o, 0.f);
    out[(size_t)node * F + lane] = o;
  }
}

extern "C" void kernel_launch(void* const* d_in, const int* in_sizes, int n_in,
                              void* d_out, int out_size, void* d_ws, size_t ws_size,
                              hipStream_t stream) {
  const float* x = (const float*)d_in[0];
  const int* ei = (const int*)d_in[1];   // int32 on device (harness converts)
  const float* W1 = (const float*)d_in[2];
  const float* b1 = (const float*)d_in[3];
  const float* W2 = (const float*)d_in[4];
  const float* b2 = (const float*)d_in[5];
  float* out = (float*)d_out;

  const int IN = 256, HID = 128;
  int N = in_sizes[0] / IN;   // 100000
  int E = in_sizes[1] / 2;    // 1600000

  char* ws = (char*)d_ws;
  size_t off = 0;
  auto alloc = [&](size_t bytes) -> void* {
    void* p = ws + off;
    off += (bytes + 255) & ~(size_t)255;
    return p;
  };
  int* cnt = (int*)alloc((size_t)N * 4);
  int* offs = (int*)alloc(((size_t)N + 1) * 4);
  int* cursor = (int*)alloc((size_t)N * 4);
  float* dinv = (float*)alloc((size_t)N * 4);
  int* bsums = (int*)alloc(1024 * 4);
  int* csr = (int*)alloc((size_t)E * 4);
  float* h1s = (float*)alloc((size_t)N * HID * 4);
  float* a1 = (float*)alloc((size_t)N * HID * 4);
  float* h2s = h1s;  // h1s dead after aggregate1 -> reuse for layer-2 GEMM out

  hipMemsetAsync(cnt, 0, (size_t)N * 4, stream);
  int eb = (E + 255) / 256;
  hist_kernel<<<eb, 256, 0, stream>>>(ei, E, cnt, N);
  int nb = (N + 1023) / 1024;  // 98 <= 256
  scan_partial<<<nb, 256, 0, stream>>>(cnt, offs, bsums, N);
  scan_bsums<<<1, 256, 0, stream>>>(bsums, nb);
  finalize_kernel<<<(N + 255) / 256, 256, 0, stream>>>(cnt, offs, cursor, dinv, bsums, N, E);
  // 512 blocks = 64 per XCD-group; each group scans all edges for its range
  fill_swz<<<512, 256, 0, stream>>>(ei, E, cursor, csr, N, (N + 7) / 8, 64);

  gemm_scaled<256, 128, 64><<<(N + 63) / 64, 256, 0, stream>>>(x, W1, dinv, h1s, N);
  aggregate_kernel<128, true><<<(N + 3) / 4, 256, 0, stream>>>(h1s, offs, csr, dinv, b1, a1, N);
  gemm_scaled<128, 64, 128><<<(N + 127) / 128, 256, 0, stream>>>(a1, W2, dinv, h2s, N);
  aggregate_kernel<64, false><<<(N + 3) / 4, 256, 0, stream>>>(h2s, offs, csr, dinv, b2, out, N);
}

// Round 5
// 583.490 us; speedup vs baseline: 1.2937x; 1.1649x over previous
//
#include <hip/hip_runtime.h>
#include <hip/hip_fp16.h>
#include <math.h>

// ---------------------------------------------------------------------------
// 2-layer GCN on MI355X — CSR pull aggregation (fp16 features) + f16 MFMA GEMM.
// edge_index arrives as int32 [2][E] flat: first E = sources, next E = targets.
//   build CSR (hist/scan/XCD-partitioned fill), dinv = rsqrt(deg+1)
//   h1s = f16( dinv .* (x @ W1) )          [MFMA 16x16x32 f16]
//   a1  = f16( relu(dinv*(sum h1s) + b1) ) [wave-per-node gather]
//   h2s = f16( dinv .* (a1 @ W2) )
//   out = f32( dinv*(sum h2s) + b2 )       [half-wave-per-node gather]
// ---------------------------------------------------------------------------

typedef _Float16 f16;
typedef _Float16 f16x2 __attribute__((ext_vector_type(2)));
typedef _Float16 f16x4 __attribute__((ext_vector_type(4)));
typedef _Float16 f16x8 __attribute__((ext_vector_type(8)));
typedef float f32x4 __attribute__((ext_vector_type(4)));

__global__ void hist_kernel(const int* __restrict__ ei, int E,
                            int* __restrict__ cnt, int N) {
  int e = blockIdx.x * blockDim.x + threadIdx.x;
  if (e < E) {
    int c = ei[(size_t)E + e];
    if ((unsigned)c < (unsigned)N) atomicAdd(&cnt[c], 1);
  }
}

__global__ __launch_bounds__(256) void scan_partial(const int* __restrict__ cnt,
                                                    int* __restrict__ offs,
                                                    int* __restrict__ bsums,
                                                    int N) {
  __shared__ int s[256];
  int t = threadIdx.x;
  int base = blockIdx.x * 1024 + t * 4;
  int v0 = (base + 0 < N) ? cnt[base + 0] : 0;
  int v1 = (base + 1 < N) ? cnt[base + 1] : 0;
  int v2 = (base + 2 < N) ? cnt[base + 2] : 0;
  int v3 = (base + 3 < N) ? cnt[base + 3] : 0;
  int sum = v0 + v1 + v2 + v3;
  s[t] = sum;
  __syncthreads();
#pragma unroll
  for (int d = 1; d < 256; d <<= 1) {
    int x = (t >= d) ? s[t - d] : 0;
    __syncthreads();
    s[t] += x;
    __syncthreads();
  }
  int excl = s[t] - sum;
  if (base + 0 < N) offs[base + 0] = excl;
  if (base + 1 < N) offs[base + 1] = excl + v0;
  if (base + 2 < N) offs[base + 2] = excl + v0 + v1;
  if (base + 3 < N) offs[base + 3] = excl + v0 + v1 + v2;
  if (t == 255) bsums[blockIdx.x] = s[255];
}

__global__ __launch_bounds__(256) void scan_bsums(int* __restrict__ bsums, int nb) {
  __shared__ int s[256];
  int t = threadIdx.x;
  int v = (t < nb) ? bsums[t] : 0;
  s[t] = v;
  __syncthreads();
#pragma unroll
  for (int d = 1; d < 256; d <<= 1) {
    int x = (t >= d) ? s[t - d] : 0;
    __syncthreads();
    s[t] += x;
    __syncthreads();
  }
  if (t < nb) bsums[t] = s[t] - v;
}

__global__ void finalize_kernel(const int* __restrict__ cnt, int* __restrict__ offs,
                                int* __restrict__ cursor, float* __restrict__ dinv,
                                const int* __restrict__ bsums, int N, int E) {
  int i = blockIdx.x * blockDim.x + threadIdx.x;
  if (i < N) {
    int o = offs[i] + bsums[i >> 10];
    offs[i] = o;
    cursor[i] = o;
    dinv[i] = 1.0f / sqrtf((float)cnt[i] + 1.0f);
    if (i == 0) offs[N] = E;
  }
}

// XCD-ownership fill: each XCD (blockIdx&7) owns 1/8 of targets -> csr lines
// write-combine in one L2 (WRITE_SIZE ~6.4MB not 105MB).
__global__ __launch_bounds__(256) void fill_swz(const int* __restrict__ ei, int E,
                                                int* __restrict__ cursor,
                                                int* __restrict__ csr,
                                                int N, int npx, int nbg) {
  int xcd = blockIdx.x & 7;
  int grp = blockIdx.x >> 3;
  int lo = xcd * npx;
  int hi = min(N, lo + npx);
  for (int e = grp * 256 + threadIdx.x; e < E; e += nbg * 256) {
    int c = ei[(size_t)E + e];
    if (c >= lo && c < hi) {
      int r = ei[e];
      if ((unsigned)r < (unsigned)N) {
        int p = atomicAdd(&cursor[c], 1);
        if ((unsigned)p < (unsigned)E) csr[p] = r;
      }
    }
  }
}

// W [K][N] f32 row-major -> Wt [N][K] f16 (transposed, for B-fragment loads)
__global__ void cvtT(const float* __restrict__ W, f16* __restrict__ Wt, int K, int N) {
  int i = blockIdx.x * 256 + threadIdx.x;
  if (i < K * N) {
    int k = i / N, n = i % N;
    Wt[(size_t)n * K + k] = (f16)W[i];
  }
}

// C = A @ B, epilogue *dinv[row], out f16. A: [M,K] (f32 or f16); Bt: [NC,K] f16.
// 256 thr / 4 waves; block tile 128 x NC, BK=64; mfma_f32_16x16x32_f16.
// A-frag: lane row=l&15, k-octet (l>>4)*8 (contiguous); B-frag same on Bt rows.
// C/D: col=lane&15, row=(l>>4)*4+reg (m89-verified). LDS rows padded +8 halves
// (stride 144B = 2-way bank alias = free); b64 reads keep 8B alignment.
template <int K, int NC, bool AHALF>
__global__ __launch_bounds__(256) void gemm_mfma(const void* __restrict__ Ain,
                                                 const f16* __restrict__ Bt,
                                                 const float* __restrict__ dinv,
                                                 f16* __restrict__ out, int M) {
  constexpr int BM = 128, BK = 64, LDR = BK + 8;
  constexpr int NF = NC / 16;
  __shared__ f16 als[BM][LDR];
  __shared__ f16 bls[NC][LDR];
  const int t = threadIdx.x;
  const int lane = t & 63, w = t >> 6;
  const int r0 = blockIdx.x * BM;

  f32x4 acc[2][NF];
#pragma unroll
  for (int fr = 0; fr < 2; ++fr)
#pragma unroll
    for (int fc = 0; fc < NF; ++fc) acc[fr][fc] = (f32x4){0.f, 0.f, 0.f, 0.f};

  for (int kt = 0; kt < K; kt += BK) {
    if constexpr (AHALF) {
      const f16* Ag = (const f16*)Ain;
#pragma unroll
      for (int i0 = 0; i0 < 4; ++i0) {
        int i = t + i0 * 256;          // 0..1023: row=i/8, ko=i%8
        int row = i >> 3, ko = i & 7;
        int gr = min(r0 + row, M - 1);
        f16x8 v = *(const f16x8*)(Ag + (size_t)gr * K + kt + ko * 8);
        *(f16x4*)&als[row][ko * 8] = __builtin_shufflevector(v, v, 0, 1, 2, 3);
        *(f16x4*)&als[row][ko * 8 + 4] = __builtin_shufflevector(v, v, 4, 5, 6, 7);
      }
    } else {
      const float* Ag = (const float*)Ain;
#pragma unroll
      for (int i0 = 0; i0 < 8; ++i0) {
        int i = t + i0 * 256;          // 0..2047: row=i/16, kq=i%16
        int row = i >> 4, kq = i & 15;
        int gr = min(r0 + row, M - 1);
        float4 v = *(const float4*)(Ag + (size_t)gr * K + kt + kq * 4);
        f16x4 h = {(f16)v.x, (f16)v.y, (f16)v.z, (f16)v.w};
        *(f16x4*)&als[row][kq * 4] = h;
      }
    }
#pragma unroll
    for (int i0 = 0; i0 < NC / 32; ++i0) {
      int i = t + i0 * 256;            // n=i/8, ko=i%8
      int n = i >> 3, ko = i & 7;
      f16x8 v = *(const f16x8*)(Bt + (size_t)n * K + kt + ko * 8);
      *(f16x4*)&bls[n][ko * 8] = __builtin_shufflevector(v, v, 0, 1, 2, 3);
      *(f16x4*)&bls[n][ko * 8 + 4] = __builtin_shufflevector(v, v, 4, 5, 6, 7);
    }
    __syncthreads();
#pragma unroll
    for (int ks = 0; ks < 2; ++ks) {
      int kb = ks * 32 + ((lane >> 4) << 3);
      f16x8 a[2];
#pragma unroll
      for (int fr = 0; fr < 2; ++fr) {
        f16x4 lo = *(const f16x4*)&als[w * 32 + fr * 16 + (lane & 15)][kb];
        f16x4 hi = *(const f16x4*)&als[w * 32 + fr * 16 + (lane & 15)][kb + 4];
        a[fr] = __builtin_shufflevector(lo, hi, 0, 1, 2, 3, 4, 5, 6, 7);
      }
#pragma unroll
      for (int fc = 0; fc < NF; ++fc) {
        f16x4 lo = *(const f16x4*)&bls[fc * 16 + (lane & 15)][kb];
        f16x4 hi = *(const f16x4*)&bls[fc * 16 + (lane & 15)][kb + 4];
        f16x8 b = __builtin_shufflevector(lo, hi, 0, 1, 2, 3, 4, 5, 6, 7);
#pragma unroll
        for (int fr = 0; fr < 2; ++fr)
          acc[fr][fc] =
              __builtin_amdgcn_mfma_f32_16x16x32_f16(a[fr], b, acc[fr][fc], 0, 0, 0);
      }
    }
    __syncthreads();
  }
#pragma unroll
  for (int fr = 0; fr < 2; ++fr) {
#pragma unroll
    for (int reg = 0; reg < 4; ++reg) {
      int row = r0 + w * 32 + fr * 16 + ((lane >> 4) << 2) + reg;
      if (row < M) {
        float s = dinv[row];
#pragma unroll
        for (int fc = 0; fc < NF; ++fc)
          out[(size_t)row * NC + fc * 16 + (lane & 15)] = (f16)(acc[fr][fc][reg] * s);
      }
    }
  }
}

// F=128 fp16 gather: wave per node, lane owns 2 dims (4B load/row).
__global__ __launch_bounds__(256) void aggregate1_f16(
    const f16* __restrict__ hs, const int* __restrict__ offs,
    const int* __restrict__ csr, const float* __restrict__ dinv,
    const float* __restrict__ bias, f16* __restrict__ out, int N) {
  int node = blockIdx.x * 4 + (threadIdx.x >> 6);
  if (node >= N) return;
  int lane = threadIdx.x & 63;
  int beg = __builtin_amdgcn_readfirstlane(offs[node]);
  int end = __builtin_amdgcn_readfirstlane(offs[node + 1]);
  float scale = dinv[node];
  f16x2 sv = *(const f16x2*)(hs + (size_t)node * 128 + lane * 2);
  float ax = (float)sv[0], ay = (float)sv[1];
  for (int j = beg; j < end; ++j) {
    int r = csr[j];
    if ((unsigned)r < (unsigned)N) {
      f16x2 v = *(const f16x2*)(hs + (size_t)r * 128 + lane * 2);
      ax += (float)v[0];
      ay += (float)v[1];
    }
  }
  float2 b = *(const float2*)(bias + lane * 2);
  float ox = fmaxf(fmaf(scale, ax, b.x), 0.f);
  float oy = fmaxf(fmaf(scale, ay, b.y), 0.f);
  f16x2 o = {(f16)ox, (f16)oy};
  *(f16x2*)(out + (size_t)node * 128 + lane * 2) = o;
}

// F=64 fp16 gather: half-wave per node, lane owns 2 dims; f32 output.
__global__ __launch_bounds__(256) void aggregate2_f16(
    const f16* __restrict__ hs, const int* __restrict__ offs,
    const int* __restrict__ csr, const float* __restrict__ dinv,
    const float* __restrict__ bias, float* __restrict__ out, int N) {
  int node = blockIdx.x * 8 + (threadIdx.x >> 5);
  if (node >= N) return;
  int sl = threadIdx.x & 31;
  int beg = offs[node], end = offs[node + 1];  // uniform within half-wave
  float scale = dinv[node];
  f16x2 sv = *(const f16x2*)(hs + (size_t)node * 64 + sl * 2);
  float ax = (float)sv[0], ay = (float)sv[1];
  for (int j = beg; j < end; ++j) {
    int r = csr[j];
    if ((unsigned)r < (unsigned)N) {
      f16x2 v = *(const f16x2*)(hs + (size_t)r * 64 + sl * 2);
      ax += (float)v[0];
      ay += (float)v[1];
    }
  }
  float2 b = *(const float2*)(bias + sl * 2);
  float2 o = {fmaf(scale, ax, b.x), fmaf(scale, ay, b.y)};
  *(float2*)(out + (size_t)node * 64 + sl * 2) = o;
}

extern "C" void kernel_launch(void* const* d_in, const int* in_sizes, int n_in,
                              void* d_out, int out_size, void* d_ws, size_t ws_size,
                              hipStream_t stream) {
  const float* x = (const float*)d_in[0];
  const int* ei = (const int*)d_in[1];
  const float* W1 = (const float*)d_in[2];
  const float* b1 = (const float*)d_in[3];
  const float* W2 = (const float*)d_in[4];
  const float* b2 = (const float*)d_in[5];
  float* out = (float*)d_out;

  const int IN = 256, HID = 128, OUT = 64;
  int N = in_sizes[0] / IN;   // 100000
  int E = in_sizes[1] / 2;    // 1600000

  char* ws = (char*)d_ws;
  size_t off = 0;
  auto alloc = [&](size_t bytes) -> void* {
    void* p = ws + off;
    off += (bytes + 255) & ~(size_t)255;
    return p;
  };
  int* cnt = (int*)alloc((size_t)N * 4);
  int* offs = (int*)alloc(((size_t)N + 1) * 4);
  int* cursor = (int*)alloc((size_t)N * 4);
  float* dinv = (float*)alloc((size_t)N * 4);
  int* bsums = (int*)alloc(1024 * 4);
  int* csr = (int*)alloc((size_t)E * 4);
  f16* Wt1 = (f16*)alloc((size_t)IN * HID * 2);
  f16* Wt2 = (f16*)alloc((size_t)HID * OUT * 2);
  f16* h1s = (f16*)alloc((size_t)N * HID * 2);
  f16* a1 = (f16*)alloc((size_t)N * HID * 2);
  f16* h2s = h1s;  // dead after aggregate1; reuse (N*OUT*2 fits)

  cvtT<<<(IN * HID + 255) / 256, 256, 0, stream>>>(W1, Wt1, IN, HID);
  cvtT<<<(HID * OUT + 255) / 256, 256, 0, stream>>>(W2, Wt2, HID, OUT);

  hipMemsetAsync(cnt, 0, (size_t)N * 4, stream);
  int eb = (E + 255) / 256;
  hist_kernel<<<eb, 256, 0, stream>>>(ei, E, cnt, N);
  int nb = (N + 1023) / 1024;
  scan_partial<<<nb, 256, 0, stream>>>(cnt, offs, bsums, N);
  scan_bsums<<<1, 256, 0, stream>>>(bsums, nb);
  finalize_kernel<<<(N + 255) / 256, 256, 0, stream>>>(cnt, offs, cursor, dinv, bsums, N, E);
  fill_swz<<<512, 256, 0, stream>>>(ei, E, cursor, csr, N, (N + 7) / 8, 64);

  int gb = (N + 127) / 128;
  gemm_mfma<256, 128, false><<<gb, 256, 0, stream>>>(x, Wt1, dinv, h1s, N);
  aggregate1_f16<<<(N + 3) / 4, 256, 0, stream>>>(h1s, offs, csr, dinv, b1, a1, N);
  gemm_mfma<128, 64, true><<<gb, 256, 0, stream>>>(a1, Wt2, dinv, h2s, N);
  aggregate2_f16<<<(N + 7) / 8, 256, 0, stream>>>(h2s, offs, csr, dinv, b2, out, N);
}

// Round 6
// 498.191 us; speedup vs baseline: 1.5152x; 1.1712x over previous
//
#include <hip/hip_runtime.h>
#include <hip/hip_fp16.h>
#include <math.h>

// ---------------------------------------------------------------------------
// 2-layer GCN on MI355X — CSR pull aggregation (fp16 features) + f16 MFMA GEMM.
// edge_index arrives as int32 [2][E] flat: first E = sources, next E = targets.
//   hist_rank: cnt[c]++ AND rank[e] = old count (8 edges/thread, batched
//              atomics -> one waitcnt per 8, not per edge)
//   scan -> offs; finalize: dinv = rsqrt(deg+1)
//   fill_rank: csr[offs[c]+rank[e]] = src  (NO atomics, fully pipelined)
//   h1s = f16( dinv .* (x @ W1) )          [MFMA 16x16x32 f16]
//   a1  = f16( relu(dinv*(sum h1s) + b1) ) [wave-per-node gather]
//   h2s = f16( dinv .* (a1 @ W2) )
//   out = f32( dinv*(sum h2s) + b2 )       [half-wave-per-node gather]
// ---------------------------------------------------------------------------

typedef _Float16 f16;
typedef _Float16 f16x2 __attribute__((ext_vector_type(2)));
typedef _Float16 f16x4 __attribute__((ext_vector_type(4)));
typedef _Float16 f16x8 __attribute__((ext_vector_type(8)));
typedef float f32x4 __attribute__((ext_vector_type(4)));

// 8 edges/thread: issue 8 independent returning-atomics, wait once, store
// ranks coalesced. Avoids the per-edge vmcnt(0) drain that made fill slow.
__global__ __launch_bounds__(256) void hist_rank(const int* __restrict__ ei, int E,
                                                 int* __restrict__ cnt,
                                                 int* __restrict__ rank, int N) {
  int base = (blockIdx.x * 256 + threadIdx.x) * 8;
  if (base + 8 <= E) {
    int4 c0 = *(const int4*)(ei + (size_t)E + base);
    int4 c1 = *(const int4*)(ei + (size_t)E + base + 4);
    int c[8] = {c0.x, c0.y, c0.z, c0.w, c1.x, c1.y, c1.z, c1.w};
    int r[8];
#pragma unroll
    for (int k = 0; k < 8; ++k)
      r[k] = ((unsigned)c[k] < (unsigned)N) ? atomicAdd(&cnt[c[k]], 1) : -1;
    int4 r0 = {r[0], r[1], r[2], r[3]};
    int4 r1 = {r[4], r[5], r[6], r[7]};
    *(int4*)(rank + base) = r0;
    *(int4*)(rank + base + 4) = r1;
  } else {
    for (int e = base; e < E; ++e) {
      int c = ei[(size_t)E + e];
      rank[e] = ((unsigned)c < (unsigned)N) ? atomicAdd(&cnt[c], 1) : -1;
    }
  }
}

__global__ __launch_bounds__(256) void scan_partial(const int* __restrict__ cnt,
                                                    int* __restrict__ offs,
                                                    int* __restrict__ bsums,
                                                    int N) {
  __shared__ int s[256];
  int t = threadIdx.x;
  int base = blockIdx.x * 1024 + t * 4;
  int v0 = (base + 0 < N) ? cnt[base + 0] : 0;
  int v1 = (base + 1 < N) ? cnt[base + 1] : 0;
  int v2 = (base + 2 < N) ? cnt[base + 2] : 0;
  int v3 = (base + 3 < N) ? cnt[base + 3] : 0;
  int sum = v0 + v1 + v2 + v3;
  s[t] = sum;
  __syncthreads();
#pragma unroll
  for (int d = 1; d < 256; d <<= 1) {
    int x = (t >= d) ? s[t - d] : 0;
    __syncthreads();
    s[t] += x;
    __syncthreads();
  }
  int excl = s[t] - sum;
  if (base + 0 < N) offs[base + 0] = excl;
  if (base + 1 < N) offs[base + 1] = excl + v0;
  if (base + 2 < N) offs[base + 2] = excl + v0 + v1;
  if (base + 3 < N) offs[base + 3] = excl + v0 + v1 + v2;
  if (t == 255) bsums[blockIdx.x] = s[255];
}

__global__ __launch_bounds__(256) void scan_bsums(int* __restrict__ bsums, int nb) {
  __shared__ int s[256];
  int t = threadIdx.x;
  int v = (t < nb) ? bsums[t] : 0;
  s[t] = v;
  __syncthreads();
#pragma unroll
  for (int d = 1; d < 256; d <<= 1) {
    int x = (t >= d) ? s[t - d] : 0;
    __syncthreads();
    s[t] += x;
    __syncthreads();
  }
  if (t < nb) bsums[t] = s[t] - v;
}

__global__ void finalize_kernel(const int* __restrict__ cnt, int* __restrict__ offs,
                                float* __restrict__ dinv,
                                const int* __restrict__ bsums, int N, int E) {
  int i = blockIdx.x * blockDim.x + threadIdx.x;
  if (i < N) {
    offs[i] += bsums[i >> 10];
    dinv[i] = 1.0f / sqrtf((float)cnt[i] + 1.0f);
    if (i == 0) offs[N] = E;
  }
}

// No atomics: dst = offs[col] + rank. 8 edges/thread, independent gathers
// and scattered stores, fully pipelined.
__global__ __launch_bounds__(256) void fill_rank(const int* __restrict__ ei,
                                                 const int* __restrict__ rank,
                                                 const int* __restrict__ offs,
                                                 int E, int* __restrict__ csr, int N) {
  int base = (blockIdx.x * 256 + threadIdx.x) * 8;
  if (base + 8 <= E) {
    int4 s0 = *(const int4*)(ei + base);
    int4 s1 = *(const int4*)(ei + base + 4);
    int4 c0 = *(const int4*)(ei + (size_t)E + base);
    int4 c1 = *(const int4*)(ei + (size_t)E + base + 4);
    int4 r0 = *(const int4*)(rank + base);
    int4 r1 = *(const int4*)(rank + base + 4);
    int s[8] = {s0.x, s0.y, s0.z, s0.w, s1.x, s1.y, s1.z, s1.w};
    int c[8] = {c0.x, c0.y, c0.z, c0.w, c1.x, c1.y, c1.z, c1.w};
    int r[8] = {r0.x, r0.y, r0.z, r0.w, r1.x, r1.y, r1.z, r1.w};
#pragma unroll
    for (int k = 0; k < 8; ++k) {
      if (r[k] >= 0 && (unsigned)c[k] < (unsigned)N && (unsigned)s[k] < (unsigned)N)
        csr[offs[c[k]] + r[k]] = s[k];
    }
  } else {
    for (int e = base; e < E; ++e) {
      int s = ei[e], c = ei[(size_t)E + e], r = rank[e];
      if (r >= 0 && (unsigned)c < (unsigned)N && (unsigned)s < (unsigned)N)
        csr[offs[c] + r] = s;
    }
  }
}

// W [K][N] f32 row-major -> Wt [N][K] f16 (transposed, for B-fragment loads)
__global__ void cvtT(const float* __restrict__ W, f16* __restrict__ Wt, int K, int N) {
  int i = blockIdx.x * 256 + threadIdx.x;
  if (i < K * N) {
    int k = i / N, n = i % N;
    Wt[(size_t)n * K + k] = (f16)W[i];
  }
}

// C = A @ B, epilogue *dinv[row], out f16. A: [M,K] (f32 or f16); Bt: [NC,K] f16.
// 256 thr / 4 waves; block tile 128 x NC, BK=64; mfma_f32_16x16x32_f16.
// C/D: col=lane&15, row=(l>>4)*4+reg (m89-verified). LDS rows padded +8 halves
// (stride 144B = 2-way bank alias = free); b64 reads keep 8B alignment.
template <int K, int NC, bool AHALF>
__global__ __launch_bounds__(256) void gemm_mfma(const void* __restrict__ Ain,
                                                 const f16* __restrict__ Bt,
                                                 const float* __restrict__ dinv,
                                                 f16* __restrict__ out, int M) {
  constexpr int BM = 128, BK = 64, LDR = BK + 8;
  constexpr int NF = NC / 16;
  __shared__ f16 als[BM][LDR];
  __shared__ f16 bls[NC][LDR];
  const int t = threadIdx.x;
  const int lane = t & 63, w = t >> 6;
  const int r0 = blockIdx.x * BM;

  f32x4 acc[2][NF];
#pragma unroll
  for (int fr = 0; fr < 2; ++fr)
#pragma unroll
    for (int fc = 0; fc < NF; ++fc) acc[fr][fc] = (f32x4){0.f, 0.f, 0.f, 0.f};

  for (int kt = 0; kt < K; kt += BK) {
    if constexpr (AHALF) {
      const f16* Ag = (const f16*)Ain;
#pragma unroll
      for (int i0 = 0; i0 < 4; ++i0) {
        int i = t + i0 * 256;          // row=i/8, ko=i%8
        int row = i >> 3, ko = i & 7;
        int gr = min(r0 + row, M - 1);
        f16x8 v = *(const f16x8*)(Ag + (size_t)gr * K + kt + ko * 8);
        *(f16x4*)&als[row][ko * 8] = __builtin_shufflevector(v, v, 0, 1, 2, 3);
        *(f16x4*)&als[row][ko * 8 + 4] = __builtin_shufflevector(v, v, 4, 5, 6, 7);
      }
    } else {
      const float* Ag = (const float*)Ain;
#pragma unroll
      for (int i0 = 0; i0 < 8; ++i0) {
        int i = t + i0 * 256;          // row=i/16, kq=i%16
        int row = i >> 4, kq = i & 15;
        int gr = min(r0 + row, M - 1);
        float4 v = *(const float4*)(Ag + (size_t)gr * K + kt + kq * 4);
        f16x4 h = {(f16)v.x, (f16)v.y, (f16)v.z, (f16)v.w};
        *(f16x4*)&als[row][kq * 4] = h;
      }
    }
#pragma unroll
    for (int i0 = 0; i0 < NC / 32; ++i0) {
      int i = t + i0 * 256;            // n=i/8, ko=i%8
      int n = i >> 3, ko = i & 7;
      f16x8 v = *(const f16x8*)(Bt + (size_t)n * K + kt + ko * 8);
      *(f16x4*)&bls[n][ko * 8] = __builtin_shufflevector(v, v, 0, 1, 2, 3);
      *(f16x4*)&bls[n][ko * 8 + 4] = __builtin_shufflevector(v, v, 4, 5, 6, 7);
    }
    __syncthreads();
#pragma unroll
    for (int ks = 0; ks < 2; ++ks) {
      int kb = ks * 32 + ((lane >> 4) << 3);
      f16x8 a[2];
#pragma unroll
      for (int fr = 0; fr < 2; ++fr) {
        f16x4 lo = *(const f16x4*)&als[w * 32 + fr * 16 + (lane & 15)][kb];
        f16x4 hi = *(const f16x4*)&als[w * 32 + fr * 16 + (lane & 15)][kb + 4];
        a[fr] = __builtin_shufflevector(lo, hi, 0, 1, 2, 3, 4, 5, 6, 7);
      }
#pragma unroll
      for (int fc = 0; fc < NF; ++fc) {
        f16x4 lo = *(const f16x4*)&bls[fc * 16 + (lane & 15)][kb];
        f16x4 hi = *(const f16x4*)&bls[fc * 16 + (lane & 15)][kb + 4];
        f16x8 b = __builtin_shufflevector(lo, hi, 0, 1, 2, 3, 4, 5, 6, 7);
#pragma unroll
        for (int fr = 0; fr < 2; ++fr)
          acc[fr][fc] =
              __builtin_amdgcn_mfma_f32_16x16x32_f16(a[fr], b, acc[fr][fc], 0, 0, 0);
      }
    }
    __syncthreads();
  }
#pragma unroll
  for (int fr = 0; fr < 2; ++fr) {
#pragma unroll
    for (int reg = 0; reg < 4; ++reg) {
      int row = r0 + w * 32 + fr * 16 + ((lane >> 4) << 2) + reg;
      if (row < M) {
        float s = dinv[row];
#pragma unroll
        for (int fc = 0; fc < NF; ++fc)
          out[(size_t)row * NC + fc * 16 + (lane & 15)] = (f16)(acc[fr][fc][reg] * s);
      }
    }
  }
}

// F=128 fp16 gather: wave per node, lane owns 2 dims (4B load/row).
__global__ __launch_bounds__(256) void aggregate1_f16(
    const f16* __restrict__ hs, const int* __restrict__ offs,
    const int* __restrict__ csr, const float* __restrict__ dinv,
    const float* __restrict__ bias, f16* __restrict__ out, int N) {
  int node = blockIdx.x * 4 + (threadIdx.x >> 6);
  if (node >= N) return;
  int lane = threadIdx.x & 63;
  int beg = __builtin_amdgcn_readfirstlane(offs[node]);
  int end = __builtin_amdgcn_readfirstlane(offs[node + 1]);
  float scale = dinv[node];
  f16x2 sv = *(const f16x2*)(hs + (size_t)node * 128 + lane * 2);
  float ax = (float)sv[0], ay = (float)sv[1];
  for (int j = beg; j < end; ++j) {
    int r = csr[j];
    if ((unsigned)r < (unsigned)N) {
      f16x2 v = *(const f16x2*)(hs + (size_t)r * 128 + lane * 2);
      ax += (float)v[0];
      ay += (float)v[1];
    }
  }
  float2 b = *(const float2*)(bias + lane * 2);
  float ox = fmaxf(fmaf(scale, ax, b.x), 0.f);
  float oy = fmaxf(fmaf(scale, ay, b.y), 0.f);
  f16x2 o = {(f16)ox, (f16)oy};
  *(f16x2*)(out + (size_t)node * 128 + lane * 2) = o;
}

// F=64 fp16 gather: half-wave per node, lane owns 2 dims; f32 output.
__global__ __launch_bounds__(256) void aggregate2_f16(
    const f16* __restrict__ hs, const int* __restrict__ offs,
    const int* __restrict__ csr, const float* __restrict__ dinv,
    const float* __restrict__ bias, float* __restrict__ out, int N) {
  int node = blockIdx.x * 8 + (threadIdx.x >> 5);
  if (node >= N) return;
  int sl = threadIdx.x & 31;
  int beg = offs[node], end = offs[node + 1];
  float scale = dinv[node];
  f16x2 sv = *(const f16x2*)(hs + (size_t)node * 64 + sl * 2);
  float ax = (float)sv[0], ay = (float)sv[1];
  for (int j = beg; j < end; ++j) {
    int r = csr[j];
    if ((unsigned)r < (unsigned)N) {
      f16x2 v = *(const f16x2*)(hs + (size_t)r * 64 + sl * 2);
      ax += (float)v[0];
      ay += (float)v[1];
    }
  }
  float2 b = *(const float2*)(bias + sl * 2);
  float2 o = {fmaf(scale, ax, b.x), fmaf(scale, ay, b.y)};
  *(float2*)(out + (size_t)node * 64 + sl * 2) = o;
}

extern "C" void kernel_launch(void* const* d_in, const int* in_sizes, int n_in,
                              void* d_out, int out_size, void* d_ws, size_t ws_size,
                              hipStream_t stream) {
  const float* x = (const float*)d_in[0];
  const int* ei = (const int*)d_in[1];
  const float* W1 = (const float*)d_in[2];
  const float* b1 = (const float*)d_in[3];
  const float* W2 = (const float*)d_in[4];
  const float* b2 = (const float*)d_in[5];
  float* out = (float*)d_out;

  const int IN = 256, HID = 128, OUT = 64;
  int N = in_sizes[0] / IN;   // 100000
  int E = in_sizes[1] / 2;    // 1600000

  char* ws = (char*)d_ws;
  size_t off = 0;
  auto alloc = [&](size_t bytes) -> void* {
    void* p = ws + off;
    off += (bytes + 255) & ~(size_t)255;
    return p;
  };
  int* cnt = (int*)alloc((size_t)N * 4);
  int* offs = (int*)alloc(((size_t)N + 1) * 4);
  int* rank = (int*)alloc((size_t)E * 4);
  float* dinv = (float*)alloc((size_t)N * 4);
  int* bsums = (int*)alloc(1024 * 4);
  int* csr = (int*)alloc((size_t)E * 4);
  f16* Wt1 = (f16*)alloc((size_t)IN * HID * 2);
  f16* Wt2 = (f16*)alloc((size_t)HID * OUT * 2);
  f16* h1s = (f16*)alloc((size_t)N * HID * 2);
  f16* a1 = (f16*)alloc((size_t)N * HID * 2);
  f16* h2s = h1s;  // dead after aggregate1; reuse (N*OUT*2 fits)

  cvtT<<<(IN * HID + 255) / 256, 256, 0, stream>>>(W1, Wt1, IN, HID);
  cvtT<<<(HID * OUT + 255) / 256, 256, 0, stream>>>(W2, Wt2, HID, OUT);

  hipMemsetAsync(cnt, 0, (size_t)N * 4, stream);
  int eb8 = (E / 8 + 255) / 256 + 1;
  hist_rank<<<eb8, 256, 0, stream>>>(ei, E, cnt, rank, N);
  int nb = (N + 1023) / 1024;
  scan_partial<<<nb, 256, 0, stream>>>(cnt, offs, bsums, N);
  scan_bsums<<<1, 256, 0, stream>>>(bsums, nb);
  finalize_kernel<<<(N + 255) / 256, 256, 0, stream>>>(cnt, offs, dinv, bsums, N, E);
  fill_rank<<<eb8, 256, 0, stream>>>(ei, rank, offs, E, csr, N);

  int gb = (N + 127) / 128;
  gemm_mfma<256, 128, false><<<gb, 256, 0, stream>>>(x, Wt1, dinv, h1s, N);
  aggregate1_f16<<<(N + 3) / 4, 256, 0, stream>>>(h1s, offs, csr, dinv, b1, a1, N);
  gemm_mfma<128, 64, true><<<gb, 256, 0, stream>>>(a1, Wt2, dinv, h2s, N);
  aggregate2_f16<<<(N + 7) / 8, 256, 0, stream>>>(h2s, offs, csr, dinv, b2, out, N);
}

// Round 7
// 399.931 us; speedup vs baseline: 1.8875x; 1.2457x over previous
//
#include <hip/hip_runtime.h>
#include <hip/hip_fp16.h>
#include <math.h>

// ---------------------------------------------------------------------------
// 2-layer GCN on MI355X — CSR pull aggregation (fp16 features) + f16 MFMA GEMM.
// edge_index arrives as int32 [2][E] flat: first E = sources, next E = targets.
//   hist_rank: cnt[c]++ AND rank[e] = old count (8 edges/thread, batched
//              atomics -> one waitcnt per 8, not per edge)
//   scan -> offs; finalize: dinv = rsqrt(deg+1)
//   fill_rank: csr[offs[c]+rank[e]] = src  (NO atomics, fully pipelined)
//   h1s = f16( dinv .* (x @ W1) )          [MFMA 16x16x32 f16]
//   a1  = f16( relu(dinv*(sum h1s) + b1) ) [shuffle-batched 8-deep gather]
//   h2s = f16( dinv .* (a1 @ W2) )
//   out = f32( dinv*(sum h2s) + b2 )       [same, half-wave groups]
// ---------------------------------------------------------------------------

typedef _Float16 f16;
typedef _Float16 f16x2 __attribute__((ext_vector_type(2)));
typedef _Float16 f16x4 __attribute__((ext_vector_type(4)));
typedef _Float16 f16x8 __attribute__((ext_vector_type(8)));
typedef float f32x4 __attribute__((ext_vector_type(4)));

// 8 edges/thread: issue 8 independent returning-atomics, wait once, store
// ranks coalesced. Avoids a per-edge vmcnt(0) drain.
__global__ __launch_bounds__(256) void hist_rank(const int* __restrict__ ei, int E,
                                                 int* __restrict__ cnt,
                                                 int* __restrict__ rank, int N) {
  int base = (blockIdx.x * 256 + threadIdx.x) * 8;
  if (base + 8 <= E) {
    int4 c0 = *(const int4*)(ei + (size_t)E + base);
    int4 c1 = *(const int4*)(ei + (size_t)E + base + 4);
    int c[8] = {c0.x, c0.y, c0.z, c0.w, c1.x, c1.y, c1.z, c1.w};
    int r[8];
#pragma unroll
    for (int k = 0; k < 8; ++k)
      r[k] = ((unsigned)c[k] < (unsigned)N) ? atomicAdd(&cnt[c[k]], 1) : -1;
    int4 r0 = {r[0], r[1], r[2], r[3]};
    int4 r1 = {r[4], r[5], r[6], r[7]};
    *(int4*)(rank + base) = r0;
    *(int4*)(rank + base + 4) = r1;
  } else {
    for (int e = base; e < E; ++e) {
      int c = ei[(size_t)E + e];
      rank[e] = ((unsigned)c < (unsigned)N) ? atomicAdd(&cnt[c], 1) : -1;
    }
  }
}

__global__ __launch_bounds__(256) void scan_partial(const int* __restrict__ cnt,
                                                    int* __restrict__ offs,
                                                    int* __restrict__ bsums,
                                                    int N) {
  __shared__ int s[256];
  int t = threadIdx.x;
  int base = blockIdx.x * 1024 + t * 4;
  int v0 = (base + 0 < N) ? cnt[base + 0] : 0;
  int v1 = (base + 1 < N) ? cnt[base + 1] : 0;
  int v2 = (base + 2 < N) ? cnt[base + 2] : 0;
  int v3 = (base + 3 < N) ? cnt[base + 3] : 0;
  int sum = v0 + v1 + v2 + v3;
  s[t] = sum;
  __syncthreads();
#pragma unroll
  for (int d = 1; d < 256; d <<= 1) {
    int x = (t >= d) ? s[t - d] : 0;
    __syncthreads();
    s[t] += x;
    __syncthreads();
  }
  int excl = s[t] - sum;
  if (base + 0 < N) offs[base + 0] = excl;
  if (base + 1 < N) offs[base + 1] = excl + v0;
  if (base + 2 < N) offs[base + 2] = excl + v0 + v1;
  if (base + 3 < N) offs[base + 3] = excl + v0 + v1 + v2;
  if (t == 255) bsums[blockIdx.x] = s[255];
}

__global__ __launch_bounds__(256) void scan_bsums(int* __restrict__ bsums, int nb) {
  __shared__ int s[256];
  int t = threadIdx.x;
  int v = (t < nb) ? bsums[t] : 0;
  s[t] = v;
  __syncthreads();
#pragma unroll
  for (int d = 1; d < 256; d <<= 1) {
    int x = (t >= d) ? s[t - d] : 0;
    __syncthreads();
    s[t] += x;
    __syncthreads();
  }
  if (t < nb) bsums[t] = s[t] - v;
}

__global__ void finalize_kernel(const int* __restrict__ cnt, int* __restrict__ offs,
                                float* __restrict__ dinv,
                                const int* __restrict__ bsums, int N, int E) {
  int i = blockIdx.x * blockDim.x + threadIdx.x;
  if (i < N) {
    offs[i] += bsums[i >> 10];
    dinv[i] = 1.0f / sqrtf((float)cnt[i] + 1.0f);
    if (i == 0) offs[N] = E;
  }
}

// No atomics: dst = offs[col] + rank. 8 edges/thread, fully pipelined.
__global__ __launch_bounds__(256) void fill_rank(const int* __restrict__ ei,
                                                 const int* __restrict__ rank,
                                                 const int* __restrict__ offs,
                                                 int E, int* __restrict__ csr, int N) {
  int base = (blockIdx.x * 256 + threadIdx.x) * 8;
  if (base + 8 <= E) {
    int4 s0 = *(const int4*)(ei + base);
    int4 s1 = *(const int4*)(ei + base + 4);
    int4 c0 = *(const int4*)(ei + (size_t)E + base);
    int4 c1 = *(const int4*)(ei + (size_t)E + base + 4);
    int4 r0 = *(const int4*)(rank + base);
    int4 r1 = *(const int4*)(rank + base + 4);
    int s[8] = {s0.x, s0.y, s0.z, s0.w, s1.x, s1.y, s1.z, s1.w};
    int c[8] = {c0.x, c0.y, c0.z, c0.w, c1.x, c1.y, c1.z, c1.w};
    int r[8] = {r0.x, r0.y, r0.z, r0.w, r1.x, r1.y, r1.z, r1.w};
#pragma unroll
    for (int k = 0; k < 8; ++k) {
      if (r[k] >= 0 && (unsigned)c[k] < (unsigned)N && (unsigned)s[k] < (unsigned)N)
        csr[offs[c[k]] + r[k]] = s[k];
    }
  } else {
    for (int e = base; e < E; ++e) {
      int s = ei[e], c = ei[(size_t)E + e], r = rank[e];
      if (r >= 0 && (unsigned)c < (unsigned)N && (unsigned)s < (unsigned)N)
        csr[offs[c] + r] = s;
    }
  }
}

// W [K][N] f32 row-major -> Wt [N][K] f16 (transposed, for B-fragment loads)
__global__ void cvtT(const float* __restrict__ W, f16* __restrict__ Wt, int K, int N) {
  int i = blockIdx.x * 256 + threadIdx.x;
  if (i < K * N) {
    int k = i / N, n = i % N;
    Wt[(size_t)n * K + k] = (f16)W[i];
  }
}

// C = A @ B, epilogue *dinv[row], out f16. A: [M,K] (f32 or f16); Bt: [NC,K] f16.
// 256 thr / 4 waves; block tile 128 x NC, BK=64; mfma_f32_16x16x32_f16.
template <int K, int NC, bool AHALF>
__global__ __launch_bounds__(256) void gemm_mfma(const void* __restrict__ Ain,
                                                 const f16* __restrict__ Bt,
                                                 const float* __restrict__ dinv,
                                                 f16* __restrict__ out, int M) {
  constexpr int BM = 128, BK = 64, LDR = BK + 8;
  constexpr int NF = NC / 16;
  __shared__ f16 als[BM][LDR];
  __shared__ f16 bls[NC][LDR];
  const int t = threadIdx.x;
  const int lane = t & 63, w = t >> 6;
  const int r0 = blockIdx.x * BM;

  f32x4 acc[2][NF];
#pragma unroll
  for (int fr = 0; fr < 2; ++fr)
#pragma unroll
    for (int fc = 0; fc < NF; ++fc) acc[fr][fc] = (f32x4){0.f, 0.f, 0.f, 0.f};

  for (int kt = 0; kt < K; kt += BK) {
    if constexpr (AHALF) {
      const f16* Ag = (const f16*)Ain;
#pragma unroll
      for (int i0 = 0; i0 < 4; ++i0) {
        int i = t + i0 * 256;          // row=i/8, ko=i%8
        int row = i >> 3, ko = i & 7;
        int gr = min(r0 + row, M - 1);
        f16x8 v = *(const f16x8*)(Ag + (size_t)gr * K + kt + ko * 8);
        *(f16x4*)&als[row][ko * 8] = __builtin_shufflevector(v, v, 0, 1, 2, 3);
        *(f16x4*)&als[row][ko * 8 + 4] = __builtin_shufflevector(v, v, 4, 5, 6, 7);
      }
    } else {
      const float* Ag = (const float*)Ain;
#pragma unroll
      for (int i0 = 0; i0 < 8; ++i0) {
        int i = t + i0 * 256;          // row=i/16, kq=i%16
        int row = i >> 4, kq = i & 15;
        int gr = min(r0 + row, M - 1);
        float4 v = *(const float4*)(Ag + (size_t)gr * K + kt + kq * 4);
        f16x4 h = {(f16)v.x, (f16)v.y, (f16)v.z, (f16)v.w};
        *(f16x4*)&als[row][kq * 4] = h;
      }
    }
#pragma unroll
    for (int i0 = 0; i0 < NC / 32; ++i0) {
      int i = t + i0 * 256;            // n=i/8, ko=i%8
      int n = i >> 3, ko = i & 7;
      f16x8 v = *(const f16x8*)(Bt + (size_t)n * K + kt + ko * 8);
      *(f16x4*)&bls[n][ko * 8] = __builtin_shufflevector(v, v, 0, 1, 2, 3);
      *(f16x4*)&bls[n][ko * 8 + 4] = __builtin_shufflevector(v, v, 4, 5, 6, 7);
    }
    __syncthreads();
#pragma unroll
    for (int ks = 0; ks < 2; ++ks) {
      int kb = ks * 32 + ((lane >> 4) << 3);
      f16x8 a[2];
#pragma unroll
      for (int fr = 0; fr < 2; ++fr) {
        f16x4 lo = *(const f16x4*)&als[w * 32 + fr * 16 + (lane & 15)][kb];
        f16x4 hi = *(const f16x4*)&als[w * 32 + fr * 16 + (lane & 15)][kb + 4];
        a[fr] = __builtin_shufflevector(lo, hi, 0, 1, 2, 3, 4, 5, 6, 7);
      }
#pragma unroll
      for (int fc = 0; fc < NF; ++fc) {
        f16x4 lo = *(const f16x4*)&bls[fc * 16 + (lane & 15)][kb];
        f16x4 hi = *(const f16x4*)&bls[fc * 16 + (lane & 15)][kb + 4];
        f16x8 b = __builtin_shufflevector(lo, hi, 0, 1, 2, 3, 4, 5, 6, 7);
#pragma unroll
        for (int fr = 0; fr < 2; ++fr)
          acc[fr][fc] =
              __builtin_amdgcn_mfma_f32_16x16x32_f16(a[fr], b, acc[fr][fc], 0, 0, 0);
      }
    }
    __syncthreads();
  }
#pragma unroll
  for (int fr = 0; fr < 2; ++fr) {
#pragma unroll
    for (int reg = 0; reg < 4; ++reg) {
      int row = r0 + w * 32 + fr * 16 + ((lane >> 4) << 2) + reg;
      if (row < M) {
        float s = dinv[row];
#pragma unroll
        for (int fc = 0; fc < NF; ++fc)
          out[(size_t)row * NC + fc * 16 + (lane & 15)] = (f16)(acc[fr][fc][reg] * s);
      }
    }
  }
}

// F=128 gather, wave per node. Lanes cooperatively load 64 csr indices in ONE
// coalesced read, then 8 independent row-gathers issue back-to-back (one
// waitcnt per 8) -> 8-deep memory pipelining instead of a serial chain.
__global__ __launch_bounds__(256) void aggregate1_f16(
    const f16* __restrict__ hs, const int* __restrict__ offs,
    const int* __restrict__ csr, const float* __restrict__ dinv,
    const float* __restrict__ bias, f16* __restrict__ out, int N) {
  int node = blockIdx.x * 4 + (threadIdx.x >> 6);
  if (node >= N) return;
  int lane = threadIdx.x & 63;
  int beg = __builtin_amdgcn_readfirstlane(offs[node]);
  int end = __builtin_amdgcn_readfirstlane(offs[node + 1]);
  float scale = dinv[node];
  f16x2 sv = *(const f16x2*)(hs + (size_t)node * 128 + lane * 2);
  float ax = (float)sv[0], ay = (float)sv[1];
  for (int j0 = beg; j0 < end; j0 += 64) {
    int cnt = min(64, end - j0);
    int myidx = 0;
    if (lane < cnt) myidx = csr[j0 + lane];
    int k = 0;
    for (; k + 8 <= cnt; k += 8) {
      f16x2 v[8];
#pragma unroll
      for (int u = 0; u < 8; ++u) {
        unsigned r = min((unsigned)__shfl(myidx, k + u), (unsigned)(N - 1));
        v[u] = *(const f16x2*)(hs + (size_t)r * 128 + lane * 2);
      }
#pragma unroll
      for (int u = 0; u < 8; ++u) {
        ax += (float)v[u][0];
        ay += (float)v[u][1];
      }
    }
    for (; k < cnt; ++k) {
      unsigned r = min((unsigned)__shfl(myidx, k), (unsigned)(N - 1));
      f16x2 v = *(const f16x2*)(hs + (size_t)r * 128 + lane * 2);
      ax += (float)v[0];
      ay += (float)v[1];
    }
  }
  float2 b = *(const float2*)(bias + lane * 2);
  float ox = fmaxf(fmaf(scale, ax, b.x), 0.f);
  float oy = fmaxf(fmaf(scale, ay, b.y), 0.f);
  f16x2 o = {(f16)ox, (f16)oy};
  *(f16x2*)(out + (size_t)node * 128 + lane * 2) = o;
}

// F=64 gather, half-wave per node: same shuffle-batched 8-deep pipeline
// (width-32 shfl); f32 output.
__global__ __launch_bounds__(256) void aggregate2_f16(
    const f16* __restrict__ hs, const int* __restrict__ offs,
    const int* __restrict__ csr, const float* __restrict__ dinv,
    const float* __restrict__ bias, float* __restrict__ out, int N) {
  int node = blockIdx.x * 8 + (threadIdx.x >> 5);
  if (node >= N) return;
  int sl = threadIdx.x & 31;
  int beg = offs[node], end = offs[node + 1];  // uniform within half-wave
  float scale = dinv[node];
  f16x2 sv = *(const f16x2*)(hs + (size_t)node * 64 + sl * 2);
  float ax = (float)sv[0], ay = (float)sv[1];
  for (int j0 = beg; j0 < end; j0 += 32) {
    int cnt = min(32, end - j0);
    int myidx = 0;
    if (sl < cnt) myidx = csr[j0 + sl];
    int k = 0;
    for (; k + 8 <= cnt; k += 8) {
      f16x2 v[8];
#pragma unroll
      for (int u = 0; u < 8; ++u) {
        unsigned r = min((unsigned)__shfl(myidx, k + u, 32), (unsigned)(N - 1));
        v[u] = *(const f16x2*)(hs + (size_t)r * 64 + sl * 2);
      }
#pragma unroll
      for (int u = 0; u < 8; ++u) {
        ax += (float)v[u][0];
        ay += (float)v[u][1];
      }
    }
    for (; k < cnt; ++k) {
      unsigned r = min((unsigned)__shfl(myidx, k, 32), (unsigned)(N - 1));
      f16x2 v = *(const f16x2*)(hs + (size_t)r * 64 + sl * 2);
      ax += (float)v[0];
      ay += (float)v[1];
    }
  }
  float2 b = *(const float2*)(bias + sl * 2);
  float2 o = {fmaf(scale, ax, b.x), fmaf(scale, ay, b.y)};
  *(float2*)(out + (size_t)node * 64 + sl * 2) = o;
}

extern "C" void kernel_launch(void* const* d_in, const int* in_sizes, int n_in,
                              void* d_out, int out_size, void* d_ws, size_t ws_size,
                              hipStream_t stream) {
  const float* x = (const float*)d_in[0];
  const int* ei = (const int*)d_in[1];
  const float* W1 = (const float*)d_in[2];
  const float* b1 = (const float*)d_in[3];
  const float* W2 = (const float*)d_in[4];
  const float* b2 = (const float*)d_in[5];
  float* out = (float*)d_out;

  const int IN = 256, HID = 128, OUT = 64;
  int N = in_sizes[0] / IN;   // 100000
  int E = in_sizes[1] / 2;    // 1600000

  char* ws = (char*)d_ws;
  size_t off = 0;
  auto alloc = [&](size_t bytes) -> void* {
    void* p = ws + off;
    off += (bytes + 255) & ~(size_t)255;
    return p;
  };
  int* cnt = (int*)alloc((size_t)N * 4);
  int* offs = (int*)alloc(((size_t)N + 1) * 4);
  int* rank = (int*)alloc((size_t)E * 4);
  float* dinv = (float*)alloc((size_t)N * 4);
  int* bsums = (int*)alloc(1024 * 4);
  int* csr = (int*)alloc((size_t)E * 4);
  f16* Wt1 = (f16*)alloc((size_t)IN * HID * 2);
  f16* Wt2 = (f16*)alloc((size_t)HID * OUT * 2);
  f16* h1s = (f16*)alloc((size_t)N * HID * 2);
  f16* a1 = (f16*)alloc((size_t)N * HID * 2);
  f16* h2s = h1s;  // dead after aggregate1; reuse (N*OUT*2 fits)

  cvtT<<<(IN * HID + 255) / 256, 256, 0, stream>>>(W1, Wt1, IN, HID);
  cvtT<<<(HID * OUT + 255) / 256, 256, 0, stream>>>(W2, Wt2, HID, OUT);

  hipMemsetAsync(cnt, 0, (size_t)N * 4, stream);
  int eb8 = (E / 8 + 255) / 256 + 1;
  hist_rank<<<eb8, 256, 0, stream>>>(ei, E, cnt, rank, N);
  int nb = (N + 1023) / 1024;
  scan_partial<<<nb, 256, 0, stream>>>(cnt, offs, bsums, N);
  scan_bsums<<<1, 256, 0, stream>>>(bsums, nb);
  finalize_kernel<<<(N + 255) / 256, 256, 0, stream>>>(cnt, offs, dinv, bsums, N, E);
  fill_rank<<<eb8, 256, 0, stream>>>(ei, rank, offs, E, csr, N);

  int gb = (N + 127) / 128;
  gemm_mfma<256, 128, false><<<gb, 256, 0, stream>>>(x, Wt1, dinv, h1s, N);
  aggregate1_f16<<<(N + 3) / 4, 256, 0, stream>>>(h1s, offs, csr, dinv, b1, a1, N);
  gemm_mfma<128, 64, true><<<gb, 256, 0, stream>>>(a1, Wt2, dinv, h2s, N);
  aggregate2_f16<<<(N + 7) / 8, 256, 0, stream>>>(h2s, offs, csr, dinv, b2, out, N);
}

// Round 8
// 398.522 us; speedup vs baseline: 1.8942x; 1.0035x over previous
//
#include <hip/hip_runtime.h>
#include <hip/hip_fp16.h>
#include <math.h>

// ---------------------------------------------------------------------------
// 2-layer GCN on MI355X — CSR pull aggregation (fp16 features) + f16 MFMA GEMM.
// edge_index arrives as int32 [2][E] flat: first E = sources, next E = targets.
//   hist_rank: cnt[c*16]++ AND rank[e] = old count. cnt padded one counter
//              per 64B line (kills memory-side same-line atomic serialization);
//              4 edges/thread over 1563 blocks (2x atomic MLP vs 8/thread).
//   scan -> offs; finalize: dinv = rsqrt(deg+1)
//   fill_rank: csr[offs[c]+rank[e]] = src  (NO atomics, fully pipelined)
//   h1s = f16( dinv .* (x @ W1) )          [MFMA 16x16x32 f16]
//   a1  = f16( relu(dinv*(sum h1s) + b1) ) [shuffle-batched 8-deep gather]
//   h2s = f16( dinv .* (a1 @ W2) )
//   out = f32( dinv*(sum h2s) + b2 )       [same, half-wave groups]
// ---------------------------------------------------------------------------

typedef _Float16 f16;
typedef _Float16 f16x2 __attribute__((ext_vector_type(2)));
typedef _Float16 f16x4 __attribute__((ext_vector_type(4)));
typedef _Float16 f16x8 __attribute__((ext_vector_type(8)));
typedef float f32x4 __attribute__((ext_vector_type(4)));

#define CPAD 16  // counters padded to one per 64B line

// 4 edges/thread: 4 independent returning-atomics in flight, one waitcnt,
// coalesced rank stores. Padded counters -> no same-line atomic contention.
__global__ __launch_bounds__(256) void hist_rank(const int* __restrict__ ei, int E,
                                                 int* __restrict__ cnt,
                                                 int* __restrict__ rank, int N) {
  int base = (blockIdx.x * 256 + threadIdx.x) * 4;
  if (base + 4 <= E) {
    int4 c4 = *(const int4*)(ei + (size_t)E + base);
    int c[4] = {c4.x, c4.y, c4.z, c4.w};
    int r[4];
#pragma unroll
    for (int k = 0; k < 4; ++k)
      r[k] = ((unsigned)c[k] < (unsigned)N) ? atomicAdd(&cnt[(size_t)c[k] * CPAD], 1)
                                            : -1;
    int4 r4 = {r[0], r[1], r[2], r[3]};
    *(int4*)(rank + base) = r4;
  } else {
    for (int e = base; e < E; ++e) {
      int c = ei[(size_t)E + e];
      rank[e] = ((unsigned)c < (unsigned)N) ? atomicAdd(&cnt[(size_t)c * CPAD], 1) : -1;
    }
  }
}

__global__ __launch_bounds__(256) void scan_partial(const int* __restrict__ cnt,
                                                    int* __restrict__ offs,
                                                    int* __restrict__ bsums,
                                                    int N) {
  __shared__ int s[256];
  int t = threadIdx.x;
  int base = blockIdx.x * 1024 + t * 4;
  int v0 = (base + 0 < N) ? cnt[(size_t)(base + 0) * CPAD] : 0;
  int v1 = (base + 1 < N) ? cnt[(size_t)(base + 1) * CPAD] : 0;
  int v2 = (base + 2 < N) ? cnt[(size_t)(base + 2) * CPAD] : 0;
  int v3 = (base + 3 < N) ? cnt[(size_t)(base + 3) * CPAD] : 0;
  int sum = v0 + v1 + v2 + v3;
  s[t] = sum;
  __syncthreads();
#pragma unroll
  for (int d = 1; d < 256; d <<= 1) {
    int x = (t >= d) ? s[t - d] : 0;
    __syncthreads();
    s[t] += x;
    __syncthreads();
  }
  int excl = s[t] - sum;
  if (base + 0 < N) offs[base + 0] = excl;
  if (base + 1 < N) offs[base + 1] = excl + v0;
  if (base + 2 < N) offs[base + 2] = excl + v0 + v1;
  if (base + 3 < N) offs[base + 3] = excl + v0 + v1 + v2;
  if (t == 255) bsums[blockIdx.x] = s[255];
}

__global__ __launch_bounds__(256) void scan_bsums(int* __restrict__ bsums, int nb) {
  __shared__ int s[256];
  int t = threadIdx.x;
  int v = (t < nb) ? bsums[t] : 0;
  s[t] = v;
  __syncthreads();
#pragma unroll
  for (int d = 1; d < 256; d <<= 1) {
    int x = (t >= d) ? s[t - d] : 0;
    __syncthreads();
    s[t] += x;
    __syncthreads();
  }
  if (t < nb) bsums[t] = s[t] - v;
}

__global__ void finalize_kernel(const int* __restrict__ cnt, int* __restrict__ offs,
                                float* __restrict__ dinv,
                                const int* __restrict__ bsums, int N, int E) {
  int i = blockIdx.x * blockDim.x + threadIdx.x;
  if (i < N) {
    offs[i] += bsums[i >> 10];
    dinv[i] = 1.0f / sqrtf((float)cnt[(size_t)i * CPAD] + 1.0f);
    if (i == 0) offs[N] = E;
  }
}

// No atomics: dst = offs[col] + rank. 8 edges/thread, fully pipelined.
__global__ __launch_bounds__(256) void fill_rank(const int* __restrict__ ei,
                                                 const int* __restrict__ rank,
                                                 const int* __restrict__ offs,
                                                 int E, int* __restrict__ csr, int N) {
  int base = (blockIdx.x * 256 + threadIdx.x) * 8;
  if (base + 8 <= E) {
    int4 s0 = *(const int4*)(ei + base);
    int4 s1 = *(const int4*)(ei + base + 4);
    int4 c0 = *(const int4*)(ei + (size_t)E + base);
    int4 c1 = *(const int4*)(ei + (size_t)E + base + 4);
    int4 r0 = *(const int4*)(rank + base);
    int4 r1 = *(const int4*)(rank + base + 4);
    int s[8] = {s0.x, s0.y, s0.z, s0.w, s1.x, s1.y, s1.z, s1.w};
    int c[8] = {c0.x, c0.y, c0.z, c0.w, c1.x, c1.y, c1.z, c1.w};
    int r[8] = {r0.x, r0.y, r0.z, r0.w, r1.x, r1.y, r1.z, r1.w};
#pragma unroll
    for (int k = 0; k < 8; ++k) {
      if (r[k] >= 0 && (unsigned)c[k] < (unsigned)N && (unsigned)s[k] < (unsigned)N)
        csr[offs[c[k]] + r[k]] = s[k];
    }
  } else {
    for (int e = base; e < E; ++e) {
      int s = ei[e], c = ei[(size_t)E + e], r = rank[e];
      if (r >= 0 && (unsigned)c < (unsigned)N && (unsigned)s < (unsigned)N)
        csr[offs[c] + r] = s;
    }
  }
}

// W [K][N] f32 row-major -> Wt [N][K] f16 (transposed, for B-fragment loads)
__global__ void cvtT(const float* __restrict__ W, f16* __restrict__ Wt, int K, int N) {
  int i = blockIdx.x * 256 + threadIdx.x;
  if (i < K * N) {
    int k = i / N, n = i % N;
    Wt[(size_t)n * K + k] = (f16)W[i];
  }
}

// C = A @ B, epilogue *dinv[row], out f16. A: [M,K] (f32 or f16); Bt: [NC,K] f16.
// 256 thr / 4 waves; block tile 128 x NC, BK=64; mfma_f32_16x16x32_f16.
template <int K, int NC, bool AHALF>
__global__ __launch_bounds__(256) void gemm_mfma(const void* __restrict__ Ain,
                                                 const f16* __restrict__ Bt,
                                                 const float* __restrict__ dinv,
                                                 f16* __restrict__ out, int M) {
  constexpr int BM = 128, BK = 64, LDR = BK + 8;
  constexpr int NF = NC / 16;
  __shared__ f16 als[BM][LDR];
  __shared__ f16 bls[NC][LDR];
  const int t = threadIdx.x;
  const int lane = t & 63, w = t >> 6;
  const int r0 = blockIdx.x * BM;

  f32x4 acc[2][NF];
#pragma unroll
  for (int fr = 0; fr < 2; ++fr)
#pragma unroll
    for (int fc = 0; fc < NF; ++fc) acc[fr][fc] = (f32x4){0.f, 0.f, 0.f, 0.f};

  for (int kt = 0; kt < K; kt += BK) {
    if constexpr (AHALF) {
      const f16* Ag = (const f16*)Ain;
#pragma unroll
      for (int i0 = 0; i0 < 4; ++i0) {
        int i = t + i0 * 256;          // row=i/8, ko=i%8
        int row = i >> 3, ko = i & 7;
        int gr = min(r0 + row, M - 1);
        f16x8 v = *(const f16x8*)(Ag + (size_t)gr * K + kt + ko * 8);
        *(f16x4*)&als[row][ko * 8] = __builtin_shufflevector(v, v, 0, 1, 2, 3);
        *(f16x4*)&als[row][ko * 8 + 4] = __builtin_shufflevector(v, v, 4, 5, 6, 7);
      }
    } else {
      const float* Ag = (const float*)Ain;
#pragma unroll
      for (int i0 = 0; i0 < 8; ++i0) {
        int i = t + i0 * 256;          // row=i/16, kq=i%16
        int row = i >> 4, kq = i & 15;
        int gr = min(r0 + row, M - 1);
        float4 v = *(const float4*)(Ag + (size_t)gr * K + kt + kq * 4);
        f16x4 h = {(f16)v.x, (f16)v.y, (f16)v.z, (f16)v.w};
        *(f16x4*)&als[row][kq * 4] = h;
      }
    }
#pragma unroll
    for (int i0 = 0; i0 < NC / 32; ++i0) {
      int i = t + i0 * 256;            // n=i/8, ko=i%8
      int n = i >> 3, ko = i & 7;
      f16x8 v = *(const f16x8*)(Bt + (size_t)n * K + kt + ko * 8);
      *(f16x4*)&bls[n][ko * 8] = __builtin_shufflevector(v, v, 0, 1, 2, 3);
      *(f16x4*)&bls[n][ko * 8 + 4] = __builtin_shufflevector(v, v, 4, 5, 6, 7);
    }
    __syncthreads();
#pragma unroll
    for (int ks = 0; ks < 2; ++ks) {
      int kb = ks * 32 + ((lane >> 4) << 3);
      f16x8 a[2];
#pragma unroll
      for (int fr = 0; fr < 2; ++fr) {
        f16x4 lo = *(const f16x4*)&als[w * 32 + fr * 16 + (lane & 15)][kb];
        f16x4 hi = *(const f16x4*)&als[w * 32 + fr * 16 + (lane & 15)][kb + 4];
        a[fr] = __builtin_shufflevector(lo, hi, 0, 1, 2, 3, 4, 5, 6, 7);
      }
#pragma unroll
      for (int fc = 0; fc < NF; ++fc) {
        f16x4 lo = *(const f16x4*)&bls[fc * 16 + (lane & 15)][kb];
        f16x4 hi = *(const f16x4*)&bls[fc * 16 + (lane & 15)][kb + 4];
        f16x8 b = __builtin_shufflevector(lo, hi, 0, 1, 2, 3, 4, 5, 6, 7);
#pragma unroll
        for (int fr = 0; fr < 2; ++fr)
          acc[fr][fc] =
              __builtin_amdgcn_mfma_f32_16x16x32_f16(a[fr], b, acc[fr][fc], 0, 0, 0);
      }
    }
    __syncthreads();
  }
#pragma unroll
  for (int fr = 0; fr < 2; ++fr) {
#pragma unroll
    for (int reg = 0; reg < 4; ++reg) {
      int row = r0 + w * 32 + fr * 16 + ((lane >> 4) << 2) + reg;
      if (row < M) {
        float s = dinv[row];
#pragma unroll
        for (int fc = 0; fc < NF; ++fc)
          out[(size_t)row * NC + fc * 16 + (lane & 15)] = (f16)(acc[fr][fc][reg] * s);
      }
    }
  }
}

// F=128 gather, wave per node. Lanes cooperatively load 64 csr indices in ONE
// coalesced read, then 8 independent row-gathers issue back-to-back (one
// waitcnt per 8) -> 8-deep memory pipelining instead of a serial chain.
__global__ __launch_bounds__(256) void aggregate1_f16(
    const f16* __restrict__ hs, const int* __restrict__ offs,
    const int* __restrict__ csr, const float* __restrict__ dinv,
    const float* __restrict__ bias, f16* __restrict__ out, int N) {
  int node = blockIdx.x * 4 + (threadIdx.x >> 6);
  if (node >= N) return;
  int lane = threadIdx.x & 63;
  int beg = __builtin_amdgcn_readfirstlane(offs[node]);
  int end = __builtin_amdgcn_readfirstlane(offs[node + 1]);
  float scale = dinv[node];
  f16x2 sv = *(const f16x2*)(hs + (size_t)node * 128 + lane * 2);
  float ax = (float)sv[0], ay = (float)sv[1];
  for (int j0 = beg; j0 < end; j0 += 64) {
    int cnt = min(64, end - j0);
    int myidx = 0;
    if (lane < cnt) myidx = csr[j0 + lane];
    int k = 0;
    for (; k + 8 <= cnt; k += 8) {
      f16x2 v[8];
#pragma unroll
      for (int u = 0; u < 8; ++u) {
        unsigned r = min((unsigned)__shfl(myidx, k + u), (unsigned)(N - 1));
        v[u] = *(const f16x2*)(hs + (size_t)r * 128 + lane * 2);
      }
#pragma unroll
      for (int u = 0; u < 8; ++u) {
        ax += (float)v[u][0];
        ay += (float)v[u][1];
      }
    }
    for (; k < cnt; ++k) {
      unsigned r = min((unsigned)__shfl(myidx, k), (unsigned)(N - 1));
      f16x2 v = *(const f16x2*)(hs + (size_t)r * 128 + lane * 2);
      ax += (float)v[0];
      ay += (float)v[1];
    }
  }
  float2 b = *(const float2*)(bias + lane * 2);
  float ox = fmaxf(fmaf(scale, ax, b.x), 0.f);
  float oy = fmaxf(fmaf(scale, ay, b.y), 0.f);
  f16x2 o = {(f16)ox, (f16)oy};
  *(f16x2*)(out + (size_t)node * 128 + lane * 2) = o;
}

// F=64 gather, half-wave per node: same shuffle-batched 8-deep pipeline
// (width-32 shfl); f32 output.
__global__ __launch_bounds__(256) void aggregate2_f16(
    const f16* __restrict__ hs, const int* __restrict__ offs,
    const int* __restrict__ csr, const float* __restrict__ dinv,
    const float* __restrict__ bias, float* __restrict__ out, int N) {
  int node = blockIdx.x * 8 + (threadIdx.x >> 5);
  if (node >= N) return;
  int sl = threadIdx.x & 31;
  int beg = offs[node], end = offs[node + 1];  // uniform within half-wave
  float scale = dinv[node];
  f16x2 sv = *(const f16x2*)(hs + (size_t)node * 64 + sl * 2);
  float ax = (float)sv[0], ay = (float)sv[1];
  for (int j0 = beg; j0 < end; j0 += 32) {
    int cnt = min(32, end - j0);
    int myidx = 0;
    if (sl < cnt) myidx = csr[j0 + sl];
    int k = 0;
    for (; k + 8 <= cnt; k += 8) {
      f16x2 v[8];
#pragma unroll
      for (int u = 0; u < 8; ++u) {
        unsigned r = min((unsigned)__shfl(myidx, k + u, 32), (unsigned)(N - 1));
        v[u] = *(const f16x2*)(hs + (size_t)r * 64 + sl * 2);
      }
#pragma unroll
      for (int u = 0; u < 8; ++u) {
        ax += (float)v[u][0];
        ay += (float)v[u][1];
      }
    }
    for (; k < cnt; ++k) {
      unsigned r = min((unsigned)__shfl(myidx, k, 32), (unsigned)(N - 1));
      f16x2 v = *(const f16x2*)(hs + (size_t)r * 64 + sl * 2);
      ax += (float)v[0];
      ay += (float)v[1];
    }
  }
  float2 b = *(const float2*)(bias + sl * 2);
  float2 o = {fmaf(scale, ax, b.x), fmaf(scale, ay, b.y)};
  *(float2*)(out + (size_t)node * 64 + sl * 2) = o;
}

extern "C" void kernel_launch(void* const* d_in, const int* in_sizes, int n_in,
                              void* d_out, int out_size, void* d_ws, size_t ws_size,
                              hipStream_t stream) {
  const float* x = (const float*)d_in[0];
  const int* ei = (const int*)d_in[1];
  const float* W1 = (const float*)d_in[2];
  const float* b1 = (const float*)d_in[3];
  const float* W2 = (const float*)d_in[4];
  const float* b2 = (const float*)d_in[5];
  float* out = (float*)d_out;

  const int IN = 256, HID = 128, OUT = 64;
  int N = in_sizes[0] / IN;   // 100000
  int E = in_sizes[1] / 2;    // 1600000

  char* ws = (char*)d_ws;
  size_t off = 0;
  auto alloc = [&](size_t bytes) -> void* {
    void* p = ws + off;
    off += (bytes + 255) & ~(size_t)255;
    return p;
  };
  int* cnt = (int*)alloc((size_t)N * CPAD * 4);  // padded: 1 counter / 64B line
  int* offs = (int*)alloc(((size_t)N + 1) * 4);
  int* rank = (int*)alloc((size_t)E * 4);
  float* dinv = (float*)alloc((size_t)N * 4);
  int* bsums = (int*)alloc(1024 * 4);
  int* csr = (int*)alloc((size_t)E * 4);
  f16* Wt1 = (f16*)alloc((size_t)IN * HID * 2);
  f16* Wt2 = (f16*)alloc((size_t)HID * OUT * 2);
  f16* h1s = (f16*)alloc((size_t)N * HID * 2);
  f16* a1 = (f16*)alloc((size_t)N * HID * 2);
  f16* h2s = h1s;  // dead after aggregate1; reuse (N*OUT*2 fits)

  cvtT<<<(IN * HID + 255) / 256, 256, 0, stream>>>(W1, Wt1, IN, HID);
  cvtT<<<(HID * OUT + 255) / 256, 256, 0, stream>>>(W2, Wt2, HID, OUT);

  hipMemsetAsync(cnt, 0, (size_t)N * CPAD * 4, stream);
  int eb4 = (E / 4 + 255) / 256 + 1;
  hist_rank<<<eb4, 256, 0, stream>>>(ei, E, cnt, rank, N);
  int nb = (N + 1023) / 1024;
  scan_partial<<<nb, 256, 0, stream>>>(cnt, offs, bsums, N);
  scan_bsums<<<1, 256, 0, stream>>>(bsums, nb);
  finalize_kernel<<<(N + 255) / 256, 256, 0, stream>>>(cnt, offs, dinv, bsums, N, E);
  int eb8 = (E / 8 + 255) / 256 + 1;
  fill_rank<<<eb8, 256, 0, stream>>>(ei, rank, offs, E, csr, N);

  int gb = (N + 127) / 128;
  gemm_mfma<256, 128, false><<<gb, 256, 0, stream>>>(x, Wt1, dinv, h1s, N);
  aggregate1_f16<<<(N + 3) / 4, 256, 0, stream>>>(h1s, offs, csr, dinv, b1, a1, N);
  gemm_mfma<128, 64, true><<<gb, 256, 0, stream>>>(a1, Wt2, dinv, h2s, N);
  aggregate2_f16<<<(N + 7) / 8, 256, 0, stream>>>(h2s, offs, csr, dinv, b2, out, N);
}